// Round 7
// baseline (1855.266 us; speedup 1.0000x reference)
//
#include <hip/hip_runtime.h>
#include <math.h>

typedef __attribute__((ext_vector_type(8))) short short8_t;
typedef __attribute__((ext_vector_type(4))) float f32x4;

#define Hh 512
#define Ww 512
#define IMG (Hh * Ww)
#define WINP 128
#define QS 325   // padded pixel-stride per q-slab (in 8-short units); 324 px used
#define NBLK 768

__device__ __forceinline__ unsigned short f2bf(float f) {
    unsigned int u = __builtin_bit_cast(unsigned int, f);
    u += 0x7fffu + ((u >> 16) & 1u);
    return (unsigned short)(u >> 16);
}
__device__ __forceinline__ float bf2f(unsigned short h) {
    unsigned int u = ((unsigned int)h) << 16;
    return __builtin_bit_cast(float, u);
}

// ---- manual grid barrier: bar[0]=count, bar[1]=generation (memset to 0 pre-launch)
__device__ __forceinline__ void gbar(unsigned int* bar) {
    __syncthreads();                       // all waves' stores drained (vmcnt0) before signal
    if (threadIdx.x == 0) {
        __threadfence();                   // agent fence: L2 writeback on this XCD
        unsigned g = atomicAdd(&bar[1], 0u);         // coherent read of generation
        unsigned arrived = atomicAdd(&bar[0], 1u);
        if (arrived == NBLK - 1u) {
            atomicSub(&bar[0], (unsigned)NBLK);      // reset count
            atomicAdd(&bar[1], 1u);                  // release
        } else {
            while (atomicAdd(&bar[1], 0u) == g)
                __builtin_amdgcn_s_sleep(1);
        }
        __threadfence();                   // invalidate L1/L2 before post-barrier reads
    }
    __syncthreads();
}

// ============================================================================
// Single megakernel, plain launch. grid 768 = 3 blocks/CU (LDS 39.2KB, VGPR<=168).
// Phases separated by manual device-scope barrier; box computed per-block.
// ============================================================================
__global__ __launch_bounds__(256, 3) void mega_kernel(
    const float* __restrict__ x, const float* __restrict__ pred,
    const float* __restrict__ feat,
    const float* __restrict__ sw, const float* __restrict__ sbias,
    const float* __restrict__ m1w, const float* __restrict__ m1b,
    const float* __restrict__ m2w, const float* __restrict__ m2b,
    const float* __restrict__ hw, const float* __restrict__ hb,
    float* __restrict__ out,
    unsigned int* __restrict__ bar,
    unsigned short* __restrict__ WF, unsigned short* __restrict__ featcl,
    unsigned short* __restrict__ fscl, float* __restrict__ Scl,
    unsigned short* __restrict__ h1cl, unsigned short* __restrict__ h2cl)
{
    const int tid = threadIdx.x;
    const int bx = blockIdx.x;
    const int l = tid & 63, w = tid >> 6;
    const int nf = w & 1;
    const int rbase = (w >> 1) * 8;

    __shared__ __align__(16) unsigned short s_a[4 * QS * 8];   // 20800 B
    __shared__ __align__(16) unsigned short s_b[9216];         // 18432 B

    // ---------- per-block box argmax (deterministic, redundant) ----------
    int y1, x1;
    {
        float best = -1.0f; int bidx = 0x7fffffff;
        for (int cand = tid; cand < 51 * 51; cand += 256) {
            int i = cand / 51, jj = cand % 51;
            int y = i * 10, xx = jj * 10;
            float T = 0.f, Bv = 0.f;
#pragma unroll
            for (int k = 0; k < 6; ++k) {
                T  += pred[((k * 3 + 0) * Hh + y) * Ww + xx];
                Bv += pred[((k * 3 + 2) * Hh + y) * Ww + xx];
            }
            float d = fabsf(1.0f - T - Bv / 6.0f);
            if (d > best || (d == best && cand < bidx)) { best = d; bidx = cand; }
        }
        float* sv = (float*)s_b;            // [0,1024)
        int*   si = (int*)(s_b + 512);      // [1024,2048)
        int*   sres = (int*)(s_b + 1024);   // [2048,...)
        sv[tid] = best; si[tid] = bidx;
        __syncthreads();
        for (int s = 128; s > 0; s >>= 1) {
            if (tid < s) {
                if (sv[tid + s] > sv[tid] || (sv[tid + s] == sv[tid] && si[tid + s] < si[tid])) {
                    sv[tid] = sv[tid + s]; si[tid] = si[tid + s];
                }
            }
            __syncthreads();
        }
        if (tid == 0) {
            int idx = si[0];
            int cy = (idx / 51) * 10, cx = (idx % 51) * 10;
            int yy = cy - 64; yy = yy < 0 ? 0 : (yy > Hh - WINP ? Hh - WINP : yy);
            int xx = cx - 64; xx = xx < 0 ? 0 : (xx > Ww - WINP ? Ww - WINP : xx);
            sres[0] = yy; sres[1] = xx;
        }
        __syncthreads();
        y1 = sres[0]; x1 = sres[1];
        __syncthreads();
    }

    // ---------- P0: weights | copy pred->out | featcl ----------
    for (int u = bx; u < 6060; u += NBLK) {
        if (u < 684) {
            int idx = u * 256 + tid;   // < 175104
            int j = idx & 7;
            int lane = (idx >> 3) & 63;
            int frag = idx >> 9;
            int n16 = lane & 15;
            int ko = (lane >> 4) * 8 + j;
            float v = 0.f;
            if (frag < 108) {
                int g = frag / 36; int r = frag % 36; int kc = r / 18; r %= 18; int tap = r / 2; int nff = r & 1;
                int oc = g * 32 + nff * 16 + n16; int ic = kc * 32 + ko;
                v = sw[(oc * 64 + ic) * 9 + tap];
            } else if (frag < 252) {
                int r = frag - 108; int half = r / 72; r %= 72; int kc = r / 18; r %= 18; int tap = r / 2; int nff = r & 1;
                int oc = half * 32 + nff * 16 + n16; int ic = kc * 32 + ko;
                if (ic < 99) v = m1w[(oc * 99 + ic) * 9 + tap];
            } else if (frag < 324) {
                int r = frag - 252; int half = r / 36; r %= 36; int kc = r / 18; r %= 18; int tap = r / 2; int nff = r & 1;
                int oc = half * 32 + nff * 16 + n16; int ic = kc * 32 + ko;
                v = m2w[(oc * 64 + ic) * 9 + tap];
            } else {
                int r = frag - 324; int kc = r / 9; int tap = r % 9;
                int ic = kc * 32 + ko;
                if (n16 < 3) v = hw[(n16 * 64 + ic) * 9 + tap];
            }
            WF[idx] = f2bf(v);
        } else if (u < 5292) {
            int i = (u - 684) * 256 + tid;
            ((float4*)out)[i] = ((const float4*)pred)[i];
        } else {
            int fu = u - 5292;          // < 768
            int row = fu & 127, k = fu >> 7;
            __syncthreads();
            for (int i = 0; i < 32; ++i) {
                int idx = tid + i * 256;
                int ic = idx >> 7, c = idx & 127;
                s_a[c * 64 + ic] = f2bf(feat[((size_t)(k * 64 + ic) * Hh + y1 + row) * Ww + x1 + c]);
            }
            __syncthreads();
            if (tid < 128) {
                unsigned short* dst = &featcl[((size_t)k * 16384 + row * 128 + tid) * 64];
                for (int i = 0; i < 8; ++i)
                    *(short8_t*)&dst[i * 8] = *(short8_t*)&s_a[tid * 64 + i * 8];
            }
        }
    }
    gbar(bar);

    for (int it = 0; it < 2; ++it) {
        // ---------- split ----------
        for (int u = bx; u < 1152; u += NBLK) {
            const int T = u & 63;
            const int ky = u >> 6;
            const int k = ky / 3, g = ky % 3;
            const int ty0 = (T >> 3) * 16, tx0 = (T & 7) * 16;

            f32x4 acc[8];
#pragma unroll
            for (int mf = 0; mf < 8; ++mf) acc[mf] = (f32x4){0.f, 0.f, 0.f, 0.f};

            const float* plg = out + (size_t)(k * 3 + g) * IMG + (size_t)y1 * Ww + x1;
            const unsigned short* fck = featcl + (size_t)k * 16384 * 64;

            for (int kc = 0; kc < 2; ++kc) {
                __syncthreads();
#pragma unroll
                for (int i = 0; i < 6; ++i) {
                    int s = tid + i * 256;
                    if (s < 1296) {
                        int pxs = s >> 2, q = s & 3;
                        int r = pxs / 18, c = pxs - r * 18;
                        int py = ty0 - 1 + r, px = tx0 - 1 + c;
                        short8_t o;
                        if (py >= 0 && py < WINP && px >= 0 && px < WINP) {
                            float pv = plg[py * Ww + px];
                            short8_t f = *(const short8_t*)&fck[(size_t)(py * WINP + px) * 64 + kc * 32 + q * 8];
#pragma unroll
                            for (int e = 0; e < 8; ++e) o[e] = (short)f2bf(bf2f((unsigned short)f[e]) * pv);
                        } else {
#pragma unroll
                            for (int e = 0; e < 8; ++e) o[e] = 0;
                        }
                        *(short8_t*)&s_a[(q * QS + pxs) * 8] = o;
                    }
                }
                {
                    const unsigned short* src = WF + (size_t)((g * 2 + kc) * 18) * 512;
#pragma unroll
                    for (int i = 0; i < 5; ++i) {
                        int cch = tid + i * 256;
                        if (cch < 1152)
                            *(short8_t*)&s_b[cch * 8] = *(const short8_t*)&src[cch * 8];
                    }
                }
                __syncthreads();
                short8_t breg[9];
#pragma unroll
                for (int tap = 0; tap < 9; ++tap)
                    breg[tap] = *(const short8_t*)&s_b[((tap * 2 + nf) * 64 + l) * 8];
#pragma unroll
                for (int r = 0; r < 10; ++r) {
                    short8_t av[3];
#pragma unroll
                    for (int dx = 0; dx < 3; ++dx)
                        av[dx] = *(const short8_t*)&s_a[((l >> 4) * QS + (rbase + r) * 18 + (l & 15) + dx) * 8];
#pragma unroll
                    for (int dy = 0; dy < 3; ++dy) {
                        const int mf = r - dy;
                        if (mf >= 0 && mf < 8) {
#pragma unroll
                            for (int dx = 0; dx < 3; ++dx)
                                acc[mf] = __builtin_amdgcn_mfma_f32_16x16x32_bf16(av[dx], breg[dy * 3 + dx], acc[mf], 0, 0, 0);
                        }
                    }
                }
            }
            __syncthreads();
            {
                float bias = sbias[g * 32 + nf * 16 + (l & 15)];
                int slot = nf * 2 + ((l & 15) >> 3);
#pragma unroll
                for (int mf = 0; mf < 8; ++mf) {
                    int row = rbase + mf;
#pragma unroll
                    for (int r = 0; r < 4; ++r) {
                        int col = (l >> 4) * 4 + r;
                        s_a[(slot * 256 + row * 16 + col) * 8 + (l & 7)] = f2bf(acc[mf][r] + bias);
                    }
                }
            }
            __syncthreads();
            {
                int row = tid >> 4, col = tid & 15;
                size_t gpx = (size_t)(ty0 + row) * WINP + tx0 + col;
                unsigned short* dst = fscl + ((size_t)k * 16384 + gpx) * 96 + g * 32;
#pragma unroll
                for (int i = 0; i < 4; ++i)
                    *(short8_t*)&dst[i * 8] = *(short8_t*)&s_a[(i * 256 + tid) * 8];
            }
        }
        gbar(bar);

        // ---------- reduce (3-way plane split; all 768 blocks busy) ----------
        {
            int gidx = bx * 256 + tid;      // 0..196607
            int p = gidx >> 16;             // plane 0..2
            int tg = gidx & 65535;
            int px = tg >> 2, q = tg & 3;
            float* d = &Scl[(size_t)px * 96 + q * 8];
            if (p == 0) {
                float s0[8], s1[8];
#pragma unroll
                for (int e = 0; e < 8; ++e) { s0[e] = 0.f; s1[e] = 0.f; }
#pragma unroll
                for (int k = 0; k < 6; ++k) {
                    const unsigned short* pp = &fscl[((size_t)k * 16384 + px) * 96 + q * 8];
                    short8_t a0 = *(const short8_t*)&pp[0];
                    short8_t a1 = *(const short8_t*)&pp[32];
#pragma unroll
                    for (int e = 0; e < 8; ++e) {
                        s0[e] += bf2f((unsigned short)a0[e]);
                        s1[e] += bf2f((unsigned short)a1[e]);
                    }
                }
#pragma unroll
                for (int e = 0; e < 8; ++e) d[e] = s1[e] * 0.2f - s0[e];
            } else if (p == 1) {
                float s0[8];
#pragma unroll
                for (int e = 0; e < 8; ++e) s0[e] = 0.f;
#pragma unroll
                for (int k = 0; k < 6; ++k) {
                    const unsigned short* pp = &fscl[((size_t)k * 16384 + px) * 96 + q * 8];
                    short8_t a0 = *(const short8_t*)&pp[0];
#pragma unroll
                    for (int e = 0; e < 8; ++e) s0[e] += bf2f((unsigned short)a0[e]);
                }
#pragma unroll
                for (int e = 0; e < 8; ++e) d[32 + e] = s0[e];
            } else {
                float s2[8];
#pragma unroll
                for (int e = 0; e < 8; ++e) s2[e] = 0.f;
#pragma unroll
                for (int k = 0; k < 6; ++k) {
                    const unsigned short* pp = &fscl[((size_t)k * 16384 + px) * 96 + q * 8];
                    short8_t a2 = *(const short8_t*)&pp[64];
#pragma unroll
                    for (int e = 0; e < 8; ++e) s2[e] += bf2f((unsigned short)a2[e]);
                }
#pragma unroll
                for (int e = 0; e < 8; ++e) d[64 + e] = s2[e] * (1.f / 6.f);
            }
        }
        gbar(bar);

        // ---------- merge1 (768 units, 1:1) ----------
        {
            const int T = bx & 63;
            const int ky = bx >> 6;
            const int k = ky >> 1, half = ky & 1;
            const int ty0 = (T >> 3) * 16, tx0 = (T & 7) * 16;

            f32x4 acc[8];
#pragma unroll
            for (int mf = 0; mf < 8; ++mf) acc[mf] = (f32x4){0.f, 0.f, 0.f, 0.f};

            for (int kc = 0; kc < 4; ++kc) {
                __syncthreads();
#pragma unroll
                for (int i = 0; i < 6; ++i) {
                    int s = tid + i * 256;
                    if (s < 1296) {
                        int pxs = s >> 2, q = s & 3;
                        int r = pxs / 18, c = pxs - r * 18;
                        int py = ty0 - 1 + r, px = tx0 - 1 + c;
                        short8_t o;
#pragma unroll
                        for (int e = 0; e < 8; ++e) o[e] = 0;
                        if (py >= 0 && py < WINP && px >= 0 && px < WINP) {
                            size_t gpx = (size_t)py * WINP + px;
                            if (kc == 0) {
                                short8_t f0 = *(const short8_t*)&fscl[((size_t)k * 16384 + gpx) * 96 + q * 8];
                                const float* S = &Scl[gpx * 96 + q * 8];
#pragma unroll
                                for (int e = 0; e < 8; ++e)
                                    o[e] = (short)f2bf(S[e] + 2.f * bf2f((unsigned short)f0[e]));
                            } else if (kc == 1) {
                                const unsigned short* fp = &fscl[((size_t)k * 16384 + gpx) * 96];
                                short8_t f0 = *(const short8_t*)&fp[q * 8];
                                short8_t f1 = *(const short8_t*)&fp[32 + q * 8];
                                const float* S = &Scl[gpx * 96 + 32 + q * 8];
#pragma unroll
                                for (int e = 0; e < 8; ++e)
                                    o[e] = (short)f2bf(S[e] - bf2f((unsigned short)f0[e]) + bf2f((unsigned short)f1[e]));
                            } else if (kc == 2) {
                                const float* S = &Scl[gpx * 96 + 64 + q * 8];
#pragma unroll
                                for (int e = 0; e < 8; ++e) o[e] = (short)f2bf(S[e]);
                            } else {
                                if (q == 0) {
#pragma unroll
                                    for (int ch = 0; ch < 3; ++ch)
                                        o[ch] = (short)f2bf(x[(size_t)(k * 3 + ch) * IMG + (size_t)(y1 + py) * Ww + x1 + px]);
                                }
                            }
                        }
                        *(short8_t*)&s_a[(q * QS + pxs) * 8] = o;
                    }
                }
                {
                    const unsigned short* src = WF + (size_t)(108 + (half * 4 + kc) * 18) * 512;
#pragma unroll
                    for (int i = 0; i < 5; ++i) {
                        int cch = tid + i * 256;
                        if (cch < 1152)
                            *(short8_t*)&s_b[cch * 8] = *(const short8_t*)&src[cch * 8];
                    }
                }
                __syncthreads();
                short8_t breg[9];
#pragma unroll
                for (int tap = 0; tap < 9; ++tap)
                    breg[tap] = *(const short8_t*)&s_b[((tap * 2 + nf) * 64 + l) * 8];
#pragma unroll
                for (int r = 0; r < 10; ++r) {
                    short8_t av[3];
#pragma unroll
                    for (int dx = 0; dx < 3; ++dx)
                        av[dx] = *(const short8_t*)&s_a[((l >> 4) * QS + (rbase + r) * 18 + (l & 15) + dx) * 8];
#pragma unroll
                    for (int dy = 0; dy < 3; ++dy) {
                        const int mf = r - dy;
                        if (mf >= 0 && mf < 8) {
#pragma unroll
                            for (int dx = 0; dx < 3; ++dx)
                                acc[mf] = __builtin_amdgcn_mfma_f32_16x16x32_bf16(av[dx], breg[dy * 3 + dx], acc[mf], 0, 0, 0);
                        }
                    }
                }
            }
            __syncthreads();
            {
                float bias = m1b[half * 32 + nf * 16 + (l & 15)];
                int slot = nf * 2 + ((l & 15) >> 3);
#pragma unroll
                for (int mf = 0; mf < 8; ++mf) {
                    int row = rbase + mf;
#pragma unroll
                    for (int r = 0; r < 4; ++r) {
                        int col = (l >> 4) * 4 + r;
                        float v = acc[mf][r] + bias;
                        v = v >= 0.f ? v : 0.2f * v;
                        s_a[(slot * 256 + row * 16 + col) * 8 + (l & 7)] = f2bf(v);
                    }
                }
            }
            __syncthreads();
            {
                int row = tid >> 4, col = tid & 15;
                size_t gpx = (size_t)(ty0 + row) * WINP + tx0 + col;
                unsigned short* dst = h1cl + ((size_t)k * 16384 + gpx) * 64 + half * 32;
#pragma unroll
                for (int i = 0; i < 4; ++i)
                    *(short8_t*)&dst[i * 8] = *(short8_t*)&s_a[(i * 256 + tid) * 8];
            }
        }
        gbar(bar);

        // ---------- merge2 (768 units, 1:1) ----------
        {
            const int T = bx & 63;
            const int ky = bx >> 6;
            const int k = ky >> 1, half = ky & 1;
            const int ty0 = (T >> 3) * 16, tx0 = (T & 7) * 16;

            f32x4 acc[8];
#pragma unroll
            for (int mf = 0; mf < 8; ++mf) acc[mf] = (f32x4){0.f, 0.f, 0.f, 0.f};

            const unsigned short* ink = h1cl + (size_t)k * 16384 * 64;

            for (int kc = 0; kc < 2; ++kc) {
                __syncthreads();
#pragma unroll
                for (int i = 0; i < 6; ++i) {
                    int s = tid + i * 256;
                    if (s < 1296) {
                        int pxs = s >> 2, q = s & 3;
                        int r = pxs / 18, c = pxs - r * 18;
                        int py = ty0 - 1 + r, px = tx0 - 1 + c;
                        short8_t o;
                        if (py >= 0 && py < WINP && px >= 0 && px < WINP) {
                            o = *(const short8_t*)&ink[(size_t)(py * WINP + px) * 64 + kc * 32 + q * 8];
                        } else {
#pragma unroll
                            for (int e = 0; e < 8; ++e) o[e] = 0;
                        }
                        *(short8_t*)&s_a[(q * QS + pxs) * 8] = o;
                    }
                }
                {
                    const unsigned short* src = WF + (size_t)(252 + (half * 2 + kc) * 18) * 512;
#pragma unroll
                    for (int i = 0; i < 5; ++i) {
                        int cch = tid + i * 256;
                        if (cch < 1152)
                            *(short8_t*)&s_b[cch * 8] = *(const short8_t*)&src[cch * 8];
                    }
                }
                __syncthreads();
                short8_t breg[9];
#pragma unroll
                for (int tap = 0; tap < 9; ++tap)
                    breg[tap] = *(const short8_t*)&s_b[((tap * 2 + nf) * 64 + l) * 8];
#pragma unroll
                for (int r = 0; r < 10; ++r) {
                    short8_t av[3];
#pragma unroll
                    for (int dx = 0; dx < 3; ++dx)
                        av[dx] = *(const short8_t*)&s_a[((l >> 4) * QS + (rbase + r) * 18 + (l & 15) + dx) * 8];
#pragma unroll
                    for (int dy = 0; dy < 3; ++dy) {
                        const int mf = r - dy;
                        if (mf >= 0 && mf < 8) {
#pragma unroll
                            for (int dx = 0; dx < 3; ++dx)
                                acc[mf] = __builtin_amdgcn_mfma_f32_16x16x32_bf16(av[dx], breg[dy * 3 + dx], acc[mf], 0, 0, 0);
                        }
                    }
                }
            }
            __syncthreads();
            {
                float bias = m2b[half * 32 + nf * 16 + (l & 15)];
                int slot = nf * 2 + ((l & 15) >> 3);
#pragma unroll
                for (int mf = 0; mf < 8; ++mf) {
                    int row = rbase + mf;
#pragma unroll
                    for (int r = 0; r < 4; ++r) {
                        int col = (l >> 4) * 4 + r;
                        s_a[(slot * 256 + row * 16 + col) * 8 + (l & 7)] = f2bf(acc[mf][r] + bias);
                    }
                }
            }
            __syncthreads();
            {
                int row = tid >> 4, col = tid & 15;
                size_t gpx = (size_t)(ty0 + row) * WINP + tx0 + col;
                unsigned short* dst = h2cl + ((size_t)k * 16384 + gpx) * 64 + half * 32;
#pragma unroll
                for (int i = 0; i < 4; ++i)
                    *(short8_t*)&dst[i * 8] = *(short8_t*)&s_a[(i * 256 + tid) * 8];
            }
        }
        gbar(bar);

        // ---------- head (294 units) ----------
        if (bx < 294) {
            const int T = bx % 49;
            const int k = bx / 49;
            const int oy0 = 10 + (T / 7) * 16, ox0 = 10 + (T % 7) * 16;

            f32x4 acc[4];
#pragma unroll
            for (int mf = 0; mf < 4; ++mf) acc[mf] = (f32x4){0.f, 0.f, 0.f, 0.f};

            const unsigned short* ink = h2cl + (size_t)k * 16384 * 64;

            for (int kc = 0; kc < 2; ++kc) {
                __syncthreads();
#pragma unroll
                for (int i = 0; i < 6; ++i) {
                    int s = tid + i * 256;
                    if (s < 1296) {
                        int pxs = s >> 2, q = s & 3;
                        int r = pxs / 18, c = pxs - r * 18;
                        int py = oy0 - 1 + r, px = ox0 - 1 + c;   // in [9,122] -> in bounds
                        *(short8_t*)&s_a[(q * QS + pxs) * 8] =
                            *(const short8_t*)&ink[(size_t)(py * WINP + px) * 64 + kc * 32 + q * 8];
                    }
                }
                {
                    const unsigned short* src = WF + (size_t)(324 + kc * 9) * 512;
#pragma unroll
                    for (int i = 0; i < 3; ++i) {
                        int cch = tid + i * 256;
                        if (cch < 576)
                            *(short8_t*)&s_b[cch * 8] = *(const short8_t*)&src[cch * 8];
                    }
                }
                __syncthreads();
                short8_t breg[9];
#pragma unroll
                for (int tap = 0; tap < 9; ++tap)
                    breg[tap] = *(const short8_t*)&s_b[(tap * 64 + l) * 8];
#pragma unroll
                for (int r = 0; r < 6; ++r) {
                    short8_t av[3];
#pragma unroll
                    for (int dx = 0; dx < 3; ++dx)
                        av[dx] = *(const short8_t*)&s_a[((l >> 4) * QS + (w * 4 + r) * 18 + (l & 15) + dx) * 8];
#pragma unroll
                    for (int dy = 0; dy < 3; ++dy) {
                        const int mf = r - dy;
                        if (mf >= 0 && mf < 4) {
#pragma unroll
                            for (int dx = 0; dx < 3; ++dx)
                                acc[mf] = __builtin_amdgcn_mfma_f32_16x16x32_bf16(av[dx], breg[dy * 3 + dx], acc[mf], 0, 0, 0);
                        }
                    }
                }
            }
            int oc = l & 15;
            if (oc < 3) {
                float bias = hb[oc];
#pragma unroll
                for (int mf = 0; mf < 4; ++mf) {
                    int row = oy0 + w * 4 + mf;
                    if (row < 118) {
#pragma unroll
                        for (int r = 0; r < 4; ++r) {
                            int col = ox0 + (l >> 4) * 4 + r;
                            if (col < 118) {
                                float v = (tanhf(acc[mf][r] + bias) + 1.0f) * 0.5f;
                                out[(size_t)(k * 3 + oc) * IMG + (size_t)(y1 + row) * Ww + x1 + col] = v;
                            }
                        }
                    }
                }
            }
        }
        if (it == 0) gbar(bar);
    }
}

extern "C" void kernel_launch(void* const* d_in, const int* in_sizes, int n_in,
                              void* d_out, int out_size, void* d_ws, size_t ws_size,
                              hipStream_t stream)
{
    const float* x       = (const float*)d_in[0];
    const float* pred    = (const float*)d_in[1];
    const float* feat    = (const float*)d_in[2];
    const float* split_w = (const float*)d_in[3];
    const float* split_b = (const float*)d_in[4];
    const float* m1w     = (const float*)d_in[5];
    const float* m1b     = (const float*)d_in[6];
    const float* m2w     = (const float*)d_in[7];
    const float* m2b     = (const float*)d_in[8];
    const float* hw      = (const float*)d_in[9];
    const float* hb      = (const float*)d_in[10];
    float* out = (float*)d_out;

    char* base = (char*)d_ws;
    size_t o = 0;
    unsigned int* bar = (unsigned int*)(base + o);         o += 256;
    unsigned short* WF = (unsigned short*)(base + o);      o += (size_t)175104 * 2;  o = (o + 255) & ~(size_t)255;
    unsigned short* featcl = (unsigned short*)(base + o);  o += (size_t)6 * 16384 * 64 * 2;
    unsigned short* fscl = (unsigned short*)(base + o);    o += (size_t)6 * 16384 * 96 * 2;
    float* Scl = (float*)(base + o);                       o += (size_t)16384 * 96 * 4;
    unsigned short* h1cl = (unsigned short*)(base + o);    o += (size_t)6 * 16384 * 64 * 2;
    unsigned short* h2cl = (unsigned short*)(base + o);    o += (size_t)6 * 16384 * 64 * 2;

    // zero barrier state (count, generation) -- workspace is poisoned each replay
    hipMemsetAsync(bar, 0, 256, stream);

    mega_kernel<<<dim3(NBLK), dim3(256), 0, stream>>>(
        x, pred, feat, split_w, split_b, m1w, m1b, m2w, m2b, hw, hb,
        out, bar, WF, featcl, fscl, Scl, h1cl, h2cl);
}